// Round 1
// baseline (2537.863 us; speedup 1.0000x reference)
//
#include <hip/hip_runtime.h>

#define N_NODE 200000
#define EMB 64
#define N_EDGES 2000000

// out = emb * sigmoid(emb @ W + b), written to two destinations (acc init + u_cur)
__global__ void gate_kernel(const float* __restrict__ emb,
                            const float* __restrict__ W,
                            const float* __restrict__ b,
                            float* __restrict__ out1,
                            float* __restrict__ out2, int n) {
    __shared__ float Wl[64 * 64];
    __shared__ float rowbuf[4][64];
    int t = threadIdx.x;
    for (int k = t; k < 4096; k += 256) Wl[k] = W[k];
    int nl = t >> 6, j = t & 63;
    int i = blockIdx.x * 4 + nl;
    if (i < n) rowbuf[nl][j] = emb[(size_t)i * 64 + j];
    __syncthreads();
    if (i >= n) return;
    float s = b[j];
#pragma unroll
    for (int k = 0; k < 64; ++k) s += rowbuf[nl][k] * Wl[k * 64 + j];
    float g = 1.0f / (1.0f + __expf(-s));
    float val = rowbuf[nl][j] * g;
    out1[(size_t)i * 64 + j] = val;
    out2[(size_t)i * 64 + j] = val;
}

__global__ void hist_kernel(const int* __restrict__ rows, int* __restrict__ cnt, int e) {
    int i = blockIdx.x * blockDim.x + threadIdx.x;
    if (i < e) atomicAdd(&cnt[rows[i]], 1);
}

// single-block chunked exclusive scan: cnt[0..n) -> row_ptr[0..n]
__global__ void scan_kernel(const int* __restrict__ cnt, int* __restrict__ row_ptr, int n) {
    __shared__ int sums[1024];
    int t = threadIdx.x;
    int chunk = (n + 1023) / 1024;
    int start = t * chunk;
    int end = min(start + chunk, n);
    int s = 0;
    for (int i = start; i < end; ++i) s += cnt[i];
    sums[t] = s;
    __syncthreads();
    for (int off = 1; off < 1024; off <<= 1) {
        int v = (t >= off) ? sums[t - off] : 0;
        __syncthreads();
        sums[t] += v;
        __syncthreads();
    }
    int run = (t == 0) ? 0 : sums[t - 1];
    for (int i = start; i < end; ++i) { row_ptr[i] = run; run += cnt[i]; }
    if (t == 1023) row_ptr[n] = run;
}

__global__ void copy_kernel(const int* __restrict__ src, int* __restrict__ dst, int n) {
    int i = blockIdx.x * blockDim.x + threadIdx.x;
    if (i < n) dst[i] = src[i];
}

__global__ void scatter_kernel(const int* __restrict__ rows, const int* __restrict__ cols,
                               const float* __restrict__ vals, int* __restrict__ fill,
                               int* __restrict__ ecol, float* __restrict__ eval, int e) {
    int i = blockIdx.x * blockDim.x + threadIdx.x;
    if (i < e) {
        int r = rows[i];
        int pos = atomicAdd(&fill[r], 1);
        ecol[pos] = cols[i];
        eval[pos] = vals[i];
    }
}

// one wave per row: y[i] = sum_e val*x[col]; acc[i] += y[i]/max(||y[i]||,eps)
__global__ void spmm_norm_acc(const int* __restrict__ row_ptr, const int* __restrict__ ecol,
                              const float* __restrict__ eval, const float* __restrict__ x,
                              float* __restrict__ y, float* __restrict__ acc, int n) {
    int t = threadIdx.x;
    int lane = t & 63;
    int i = blockIdx.x * 4 + (t >> 6);
    if (i >= n) return;
    int s = row_ptr[i], e = row_ptr[i + 1];
    float a = 0.0f;
    for (int k = s; k < e; ++k) {
        int c = ecol[k];
        float v = eval[k];
        a += v * x[(size_t)c * 64 + lane];
    }
    y[(size_t)i * 64 + lane] = a;
    float sq = a * a;
#pragma unroll
    for (int off = 32; off; off >>= 1) sq += __shfl_xor(sq, off);
    float norm = sqrtf(sq);
    acc[(size_t)i * 64 + lane] += a / fmaxf(norm, 1e-12f);
}

// v[k] = sum_j att_m[k][j] * att[j]
__global__ void vvec_kernel(const float* __restrict__ att_m, const float* __restrict__ att,
                            float* __restrict__ v) {
    int k = threadIdx.x;
    float s = 0.0f;
    for (int j = 0; j < 64; ++j) s += att_m[k * 64 + j] * att[j];
    v[k] = s;
}

// per-node: w2=e2.v, w3=e3.v, softmax, mixed = s2*e2+s3*e3 (in place over e2)
__global__ void mix_kernel(float* __restrict__ e2io, const float* __restrict__ e3,
                           const float* __restrict__ v, float* __restrict__ score, int n) {
    int t = threadIdx.x;
    int lane = t & 63;
    int i = blockIdx.x * 4 + (t >> 6);
    if (i >= n) return;
    float a2 = e2io[(size_t)i * 64 + lane];
    float a3 = e3[(size_t)i * 64 + lane];
    float vv = v[lane];
    float w2 = a2 * vv, w3 = a3 * vv;
#pragma unroll
    for (int off = 32; off; off >>= 1) {
        w2 += __shfl_xor(w2, off);
        w3 += __shfl_xor(w3, off);
    }
    float m = fmaxf(w2, w3);
    float x2 = __expf(w2 - m), x3 = __expf(w3 - m);
    float inv = 1.0f / (x2 + x3);
    float s2 = x2 * inv, s3 = x3 * inv;
    e2io[(size_t)i * 64 + lane] = s2 * a2 + s3 * a3;
    if (lane == 0) { score[(size_t)i * 2] = s2; score[(size_t)i * 2 + 1] = s3; }
}

extern "C" void kernel_launch(void* const* d_in, const int* in_sizes, int n_in,
                              void* d_out, int out_size, void* d_ws, size_t ws_size,
                              hipStream_t stream) {
    const float* user_emb = (const float*)d_in[0];
    const float* W0 = (const float*)d_in[1];
    const float* b0 = (const float*)d_in[2];
    const float* W1 = (const float*)d_in[3];
    const float* b1 = (const float*)d_in[4];
    const float* att = (const float*)d_in[5];
    const float* att_m = (const float*)d_in[6];
    const int* item_rows = (const int*)d_in[7];
    const int* item_cols = (const int*)d_in[8];
    const float* item_vals = (const float*)d_in[9];
    const int* user_rows = (const int*)d_in[10];
    const int* user_cols = (const int*)d_in[11];
    const float* user_vals = (const float*)d_in[12];

    float* out = (float*)d_out;
    float* mixed = out;                          // N*64, doubles as acc2
    float* score = out + (size_t)N_NODE * 64;

    char* w = (char*)d_ws;
    float* acc3 = (float*)w;   w += (size_t)N_NODE * 64 * 4;
    float* u_cur = (float*)w;  w += (size_t)N_NODE * 64 * 4;
    float* u_nxt = (float*)w;  w += (size_t)N_NODE * 64 * 4;
    int* row_ptr = (int*)w;    w += ((size_t)N_NODE + 64) * 4;
    int* fill = (int*)w;       w += (size_t)N_NODE * 4;   // also the histogram buffer
    int* ecol = (int*)w;       w += (size_t)N_EDGES * 4;
    float* eval = (float*)w;   w += (size_t)N_EDGES * 4;
    float* vvec = (float*)w;   w += 256;

    const int EB = (N_EDGES + 255) / 256;
    const int NB4 = (N_NODE + 3) / 4;

    auto build_csr = [&](const int* rows, const int* cols, const float* vals) {
        hipMemsetAsync(fill, 0, (size_t)N_NODE * 4, stream);
        hist_kernel<<<EB, 256, 0, stream>>>(rows, fill, N_EDGES);
        scan_kernel<<<1, 1024, 0, stream>>>(fill, row_ptr, N_NODE);
        copy_kernel<<<(N_NODE + 255) / 256, 256, 0, stream>>>(row_ptr, fill, N_NODE);
        scatter_kernel<<<EB, 256, 0, stream>>>(rows, cols, vals, fill, ecol, eval, N_EDGES);
    };

    auto propagate = [&](float* acc) {
        float* x = u_cur;
        float* y = u_nxt;
        for (int L = 0; L < 3; ++L) {
            spmm_norm_acc<<<NB4, 256, 0, stream>>>(row_ptr, ecol, eval, x, y, acc, N_NODE);
            float* tmp = x; x = y; y = tmp;
        }
    };

    // channel 2: item graph with W0/b0, acc lives in d_out (mixed region)
    build_csr(item_rows, item_cols, item_vals);
    gate_kernel<<<NB4, 256, 0, stream>>>(user_emb, W0, b0, mixed, u_cur, N_NODE);
    propagate(mixed);

    // channel 3: user graph with W1/b1
    build_csr(user_rows, user_cols, user_vals);
    gate_kernel<<<NB4, 256, 0, stream>>>(user_emb, W1, b1, acc3, u_cur, N_NODE);
    propagate(acc3);

    // channel attention + mix
    vvec_kernel<<<1, 64, 0, stream>>>(att_m, att, vvec);
    mix_kernel<<<NB4, 256, 0, stream>>>(mixed, acc3, vvec, score, N_NODE);
}

// Round 2
// 1919.037 us; speedup vs baseline: 1.3225x; 1.3225x over previous
//
#include <hip/hip_runtime.h>

#define N_NODE 200000
#define EMB 64
#define N_EDGES 2000000
#define SCAN_CHUNK 1024            // elements per block in the device-wide scan
#define SCAN_BLOCKS ((N_NODE + SCAN_CHUNK - 1) / SCAN_CHUNK)   // 196

// out = emb * sigmoid(emb @ W + b), written to two destinations (acc init + u_cur)
__global__ void gate_kernel(const float* __restrict__ emb,
                            const float* __restrict__ W,
                            const float* __restrict__ b,
                            float* __restrict__ out1,
                            float* __restrict__ out2, int n) {
    __shared__ float Wl[64 * 64];
    __shared__ float rowbuf[4][64];
    int t = threadIdx.x;
    for (int k = t; k < 4096; k += 256) Wl[k] = W[k];
    int nl = t >> 6, j = t & 63;
    int i = blockIdx.x * 4 + nl;
    if (i < n) rowbuf[nl][j] = emb[(size_t)i * 64 + j];
    __syncthreads();
    if (i >= n) return;
    float s = b[j];
#pragma unroll
    for (int k = 0; k < 64; ++k) s += rowbuf[nl][k] * Wl[k * 64 + j];
    float g = 1.0f / (1.0f + __expf(-s));
    float val = rowbuf[nl][j] * g;
    out1[(size_t)i * 64 + j] = val;
    out2[(size_t)i * 64 + j] = val;
}

__global__ void hist_kernel(const int* __restrict__ rows, int* __restrict__ cnt, int e) {
    int i = blockIdx.x * blockDim.x + threadIdx.x;
    if (i < e) atomicAdd(&cnt[rows[i]], 1);
}

// ---- device-wide exclusive scan of cnt[0..N_NODE) -> row_ptr & fill ----
// pass 1: per-block partial sums (256 thr × 4 elem = 1024/block)
__global__ void scan1_kernel(const int* __restrict__ cnt, int* __restrict__ bsum, int n) {
    int t = threadIdx.x;
    int base = blockIdx.x * SCAN_CHUNK + t * 4;
    int s = 0;
#pragma unroll
    for (int k = 0; k < 4; ++k) {
        int i = base + k;
        if (i < n) s += cnt[i];
    }
    // wave reduce (64 lanes)
#pragma unroll
    for (int off = 32; off; off >>= 1) s += __shfl_xor(s, off);
    __shared__ int ws[4];
    int lane = t & 63, w = t >> 6;
    if (lane == 0) ws[w] = s;
    __syncthreads();
    if (t == 0) bsum[blockIdx.x] = ws[0] + ws[1] + ws[2] + ws[3];
}

// pass 2: single small block scans the SCAN_BLOCKS partial sums (exclusive)
__global__ void scan2_kernel(const int* __restrict__ bsum, int* __restrict__ boff) {
    __shared__ int sh[256];
    int t = threadIdx.x;
    int v = (t < SCAN_BLOCKS) ? bsum[t] : 0;
    sh[t] = v;
    __syncthreads();
    for (int off = 1; off < 256; off <<= 1) {
        int u = (t >= off) ? sh[t - off] : 0;
        __syncthreads();
        sh[t] += u;
        __syncthreads();
    }
    if (t < SCAN_BLOCKS) boff[t] = sh[t] - v;   // exclusive
}

// pass 3: per-block exclusive scan + block offset; writes row_ptr AND fill
__global__ void scan3_kernel(const int* __restrict__ cnt, const int* __restrict__ boff,
                             int* __restrict__ row_ptr, int* __restrict__ fill, int n) {
    int t = threadIdx.x;
    int lane = t & 63, w = t >> 6;
    int base = blockIdx.x * SCAN_CHUNK + t * 4;
    int c[4];
#pragma unroll
    for (int k = 0; k < 4; ++k) {
        int i = base + k;
        c[k] = (i < n) ? cnt[i] : 0;
    }
    int e0 = 0, e1 = c[0], e2 = c[0] + c[1], e3 = c[0] + c[1] + c[2];
    int tsum = e3 + c[3];
    // wave inclusive scan of tsum
    int incl = tsum;
#pragma unroll
    for (int off = 1; off < 64; off <<= 1) {
        int u = __shfl_up(incl, off);
        if (lane >= off) incl += u;
    }
    int excl = incl - tsum;
    __shared__ int wsum[4];
    if (lane == 63) wsum[w] = incl;
    __syncthreads();
    int woff = 0;
    for (int k = 0; k < 4; ++k) if (k < w) woff += wsum[k];
    int g = boff[blockIdx.x] + woff + excl;
    int v0 = g + e0, v1 = g + e1, v2 = g + e2, v3 = g + e3;
#pragma unroll
    for (int k = 0; k < 4; ++k) {
        int i = base + k;
        int val = (k == 0) ? v0 : (k == 1) ? v1 : (k == 2) ? v2 : v3;
        if (i < n) { row_ptr[i] = val; fill[i] = val; }
    }
    if (blockIdx.x == 0 && t == 0) row_ptr[n] = N_EDGES;
}

__global__ void scatter_kernel(const int* __restrict__ rows, const int* __restrict__ cols,
                               const float* __restrict__ vals, int* __restrict__ fill,
                               int* __restrict__ ecol, float* __restrict__ eval, int e) {
    int i = blockIdx.x * blockDim.x + threadIdx.x;
    if (i < e) {
        int r = rows[i];
        int pos = atomicAdd(&fill[r], 1);
        ecol[pos] = cols[i];
        eval[pos] = vals[i];
    }
}

// one wave per row: y[i] = sum_e val*x[col]; acc[i] += y[i]/max(||y[i]||,eps)
__global__ void spmm_norm_acc(const int* __restrict__ row_ptr, const int* __restrict__ ecol,
                              const float* __restrict__ eval, const float* __restrict__ x,
                              float* __restrict__ y, float* __restrict__ acc, int n) {
    int t = threadIdx.x;
    int lane = t & 63;
    int i = blockIdx.x * 4 + (t >> 6);
    if (i >= n) return;
    int s = row_ptr[i], e = row_ptr[i + 1];
    float a = 0.0f;
    for (int k = s; k < e; ++k) {
        int c = ecol[k];
        float v = eval[k];
        a += v * x[(size_t)c * 64 + lane];
    }
    y[(size_t)i * 64 + lane] = a;
    float sq = a * a;
#pragma unroll
    for (int off = 32; off; off >>= 1) sq += __shfl_xor(sq, off);
    float norm = sqrtf(sq);
    acc[(size_t)i * 64 + lane] += a / fmaxf(norm, 1e-12f);
}

// v[k] = sum_j att_m[k][j] * att[j]
__global__ void vvec_kernel(const float* __restrict__ att_m, const float* __restrict__ att,
                            float* __restrict__ v) {
    int k = threadIdx.x;
    float s = 0.0f;
    for (int j = 0; j < 64; ++j) s += att_m[k * 64 + j] * att[j];
    v[k] = s;
}

// per-node: w2=e2.v, w3=e3.v, softmax, mixed = s2*e2+s3*e3 (in place over e2)
__global__ void mix_kernel(float* __restrict__ e2io, const float* __restrict__ e3,
                           const float* __restrict__ v, float* __restrict__ score, int n) {
    int t = threadIdx.x;
    int lane = t & 63;
    int i = blockIdx.x * 4 + (t >> 6);
    if (i >= n) return;
    float a2 = e2io[(size_t)i * 64 + lane];
    float a3 = e3[(size_t)i * 64 + lane];
    float vv = v[lane];
    float w2 = a2 * vv, w3 = a3 * vv;
#pragma unroll
    for (int off = 32; off; off >>= 1) {
        w2 += __shfl_xor(w2, off);
        w3 += __shfl_xor(w3, off);
    }
    float m = fmaxf(w2, w3);
    float x2 = __expf(w2 - m), x3 = __expf(w3 - m);
    float inv = 1.0f / (x2 + x3);
    float s2 = x2 * inv, s3 = x3 * inv;
    e2io[(size_t)i * 64 + lane] = s2 * a2 + s3 * a3;
    if (lane == 0) { score[(size_t)i * 2] = s2; score[(size_t)i * 2 + 1] = s3; }
}

extern "C" void kernel_launch(void* const* d_in, const int* in_sizes, int n_in,
                              void* d_out, int out_size, void* d_ws, size_t ws_size,
                              hipStream_t stream) {
    const float* user_emb = (const float*)d_in[0];
    const float* W0 = (const float*)d_in[1];
    const float* b0 = (const float*)d_in[2];
    const float* W1 = (const float*)d_in[3];
    const float* b1 = (const float*)d_in[4];
    const float* att = (const float*)d_in[5];
    const float* att_m = (const float*)d_in[6];
    const int* item_rows = (const int*)d_in[7];
    const int* item_cols = (const int*)d_in[8];
    const float* item_vals = (const float*)d_in[9];
    const int* user_rows = (const int*)d_in[10];
    const int* user_cols = (const int*)d_in[11];
    const float* user_vals = (const float*)d_in[12];

    float* out = (float*)d_out;
    float* mixed = out;                          // N*64, doubles as acc2
    float* score = out + (size_t)N_NODE * 64;

    char* w = (char*)d_ws;
    float* acc3 = (float*)w;   w += (size_t)N_NODE * 64 * 4;
    float* u_cur = (float*)w;  w += (size_t)N_NODE * 64 * 4;
    float* u_nxt = (float*)w;  w += (size_t)N_NODE * 64 * 4;
    int* row_ptr = (int*)w;    w += ((size_t)N_NODE + 64) * 4;
    int* fill = (int*)w;       w += (size_t)N_NODE * 4;   // histogram + scatter cursor
    int* ecol = (int*)w;       w += (size_t)N_EDGES * 4;
    float* eval = (float*)w;   w += (size_t)N_EDGES * 4;
    float* vvec = (float*)w;   w += 256;
    int* bsum = (int*)w;       w += SCAN_BLOCKS * 4;
    int* boff = (int*)w;       w += SCAN_BLOCKS * 4;

    const int EB = (N_EDGES + 255) / 256;
    const int NB4 = (N_NODE + 3) / 4;

    auto build_csr = [&](const int* rows, const int* cols, const float* vals) {
        hipMemsetAsync(fill, 0, (size_t)N_NODE * 4, stream);
        hist_kernel<<<EB, 256, 0, stream>>>(rows, fill, N_EDGES);
        scan1_kernel<<<SCAN_BLOCKS, 256, 0, stream>>>(fill, bsum, N_NODE);
        scan2_kernel<<<1, 256, 0, stream>>>(bsum, boff);
        scan3_kernel<<<SCAN_BLOCKS, 256, 0, stream>>>(fill, boff, row_ptr, fill, N_NODE);
        scatter_kernel<<<EB, 256, 0, stream>>>(rows, cols, vals, fill, ecol, eval, N_EDGES);
    };

    auto propagate = [&](float* acc) {
        float* x = u_cur;
        float* y = u_nxt;
        for (int L = 0; L < 3; ++L) {
            spmm_norm_acc<<<NB4, 256, 0, stream>>>(row_ptr, ecol, eval, x, y, acc, N_NODE);
            float* tmp = x; x = y; y = tmp;
        }
    };

    // channel 2: item graph with W0/b0, acc lives in d_out (mixed region)
    build_csr(item_rows, item_cols, item_vals);
    gate_kernel<<<NB4, 256, 0, stream>>>(user_emb, W0, b0, mixed, u_cur, N_NODE);
    propagate(mixed);

    // channel 3: user graph with W1/b1
    build_csr(user_rows, user_cols, user_vals);
    gate_kernel<<<NB4, 256, 0, stream>>>(user_emb, W1, b1, acc3, u_cur, N_NODE);
    propagate(acc3);

    // channel attention + mix
    vvec_kernel<<<1, 64, 0, stream>>>(att_m, att, vvec);
    mix_kernel<<<NB4, 256, 0, stream>>>(mixed, acc3, vvec, score, N_NODE);
}

// Round 3
// 1219.869 us; speedup vs baseline: 2.0804x; 1.5732x over previous
//
#include <hip/hip_runtime.h>

#define N_NODE 200000
#define EMB 64
#define N_EDGES 2000000
#define CSR_N (2 * N_NODE)              // both graphs' counters concatenated
#define TOT_E (2 * N_EDGES)
#define SCAN_CHUNK 1024
#define SCAN_BLOCKS ((CSR_N + SCAN_CHUNK - 1) / SCAN_CHUNK)   // 391

// out = emb * sigmoid(emb @ W + b), written to two destinations (acc init + u_cur)
__global__ void gate_kernel(const float* __restrict__ emb,
                            const float* __restrict__ W,
                            const float* __restrict__ b,
                            float* __restrict__ out1,
                            float* __restrict__ out2, int n) {
    __shared__ float Wl[64 * 64];
    __shared__ float rowbuf[4][64];
    int t = threadIdx.x;
    for (int k = t; k < 4096; k += 256) Wl[k] = W[k];
    int nl = t >> 6, j = t & 63;
    int i = blockIdx.x * 4 + nl;
    if (i < n) rowbuf[nl][j] = emb[(size_t)i * 64 + j];
    __syncthreads();
    if (i >= n) return;
    float s = b[j];
#pragma unroll
    for (int k = 0; k < 64; ++k) s += rowbuf[nl][k] * Wl[k * 64 + j];
    float g = 1.0f / (1.0f + __expf(-s));
    float val = rowbuf[nl][j] * g;
    out1[(size_t)i * 64 + j] = val;
    out2[(size_t)i * 64 + j] = val;
}

// histogram both graphs into one counter array: item -> cnt[r], user -> cnt[N+r]
__global__ void hist2_kernel(const int* __restrict__ item_rows,
                             const int* __restrict__ user_rows,
                             int* __restrict__ cnt) {
    int i = blockIdx.x * blockDim.x + threadIdx.x;
    if (i < N_EDGES) atomicAdd(&cnt[item_rows[i]], 1);
    else if (i < TOT_E) atomicAdd(&cnt[N_NODE + user_rows[i - N_EDGES]], 1);
}

// ---- device-wide exclusive scan of cnt[0..CSR_N) -> row_ptr & fill ----
__global__ void scan1_kernel(const int* __restrict__ cnt, int* __restrict__ bsum, int n) {
    int t = threadIdx.x;
    int base = blockIdx.x * SCAN_CHUNK + t * 4;
    int s = 0;
#pragma unroll
    for (int k = 0; k < 4; ++k) {
        int i = base + k;
        if (i < n) s += cnt[i];
    }
#pragma unroll
    for (int off = 32; off; off >>= 1) s += __shfl_xor(s, off);
    __shared__ int ws[4];
    int lane = t & 63, w = t >> 6;
    if (lane == 0) ws[w] = s;
    __syncthreads();
    if (t == 0) bsum[blockIdx.x] = ws[0] + ws[1] + ws[2] + ws[3];
}

__global__ void scan2_kernel(const int* __restrict__ bsum, int* __restrict__ boff) {
    __shared__ int sh[512];
    int t = threadIdx.x;   // 512 threads
    int v = (t < SCAN_BLOCKS) ? bsum[t] : 0;
    sh[t] = v;
    __syncthreads();
    for (int off = 1; off < 512; off <<= 1) {
        int u = (t >= off) ? sh[t - off] : 0;
        __syncthreads();
        sh[t] += u;
        __syncthreads();
    }
    if (t < SCAN_BLOCKS) boff[t] = sh[t] - v;   // exclusive
}

__global__ void scan3_kernel(const int* __restrict__ cnt, const int* __restrict__ boff,
                             int* __restrict__ row_ptr, int* __restrict__ fill, int n) {
    int t = threadIdx.x;
    int lane = t & 63, w = t >> 6;
    int base = blockIdx.x * SCAN_CHUNK + t * 4;
    int c[4];
#pragma unroll
    for (int k = 0; k < 4; ++k) {
        int i = base + k;
        c[k] = (i < n) ? cnt[i] : 0;
    }
    int e1 = c[0], e2 = c[0] + c[1], e3 = c[0] + c[1] + c[2];
    int tsum = e3 + c[3];
    int incl = tsum;
#pragma unroll
    for (int off = 1; off < 64; off <<= 1) {
        int u = __shfl_up(incl, off);
        if (lane >= off) incl += u;
    }
    int excl = incl - tsum;
    __shared__ int wsum[4];
    if (lane == 63) wsum[w] = incl;
    __syncthreads();
    int woff = 0;
    for (int k = 0; k < 4; ++k) if (k < w) woff += wsum[k];
    int g = boff[blockIdx.x] + woff + excl;
    int vv[4] = {g, g + e1, g + e2, g + e3};
#pragma unroll
    for (int k = 0; k < 4; ++k) {
        int i = base + k;
        if (i < n) { row_ptr[i] = vv[k]; fill[i] = vv[k]; }
    }
    if (blockIdx.x == 0 && t == 0) row_ptr[n] = TOT_E;
}

// scatter both graphs into one packed (col, val) array
__global__ void scatter2_kernel(const int* __restrict__ item_rows, const int* __restrict__ item_cols,
                                const float* __restrict__ item_vals,
                                const int* __restrict__ user_rows, const int* __restrict__ user_cols,
                                const float* __restrict__ user_vals,
                                int* __restrict__ fill, int2* __restrict__ ecv) {
    int i = blockIdx.x * blockDim.x + threadIdx.x;
    int slot, c; float v;
    if (i < N_EDGES) {
        slot = item_rows[i]; c = item_cols[i]; v = item_vals[i];
    } else if (i < TOT_E) {
        int j = i - N_EDGES;
        slot = N_NODE + user_rows[j]; c = user_cols[j]; v = user_vals[j];
    } else return;
    int pos = atomicAdd(&fill[slot], 1);
    ecv[pos] = make_int2(c, __float_as_int(v));
}

// one wave per row; per-lane edge staging + shfl broadcast + unroll-8 gathers
template <bool WRITE_Y>
__global__ void spmm_norm_acc(const int* __restrict__ row_ptr, const int2* __restrict__ ecv,
                              const float* __restrict__ x,
                              float* __restrict__ y, float* __restrict__ acc, int n) {
    int t = threadIdx.x;
    int lane = t & 63;
    int i = blockIdx.x * 4 + (t >> 6);
    if (i >= n) return;
    int s = row_ptr[i], e = row_ptr[i + 1];
    float a = 0.0f;
    for (int base = s; base < e; base += 64) {
        int idx = base + lane;
        int cl = 0; float vl = 0.0f;
        if (idx < e) { int2 p = ecv[idx]; cl = p.x; vl = __int_as_float(p.y); }
        int cnt = min(64, e - base);
        int cnt8 = (cnt + 7) & ~7;
        for (int k = 0; k < cnt8; k += 8) {
#pragma unroll
            for (int u = 0; u < 8; ++u) {
                int c = __shfl(cl, k + u);
                float v = __shfl(vl, k + u);
                a += v * x[(size_t)c * 64 + lane];   // padding lanes: v=0, c=0 (safe, hot)
            }
        }
    }
    if (WRITE_Y) y[(size_t)i * 64 + lane] = a;
    float sq = a * a;
#pragma unroll
    for (int off = 32; off; off >>= 1) sq += __shfl_xor(sq, off);
    float norm = sqrtf(sq);
    acc[(size_t)i * 64 + lane] += a / fmaxf(norm, 1e-12f);
}

// channel-3 last layer fused with channel attention + mix (no y/acc3 writes)
__global__ void spmm_norm_mix(const int* __restrict__ row_ptr, const int2* __restrict__ ecv,
                              const float* __restrict__ x, const float* __restrict__ acc3,
                              float* __restrict__ mixed, const float* __restrict__ vvec,
                              float* __restrict__ score, int n) {
    int t = threadIdx.x;
    int lane = t & 63;
    int i = blockIdx.x * 4 + (t >> 6);
    if (i >= n) return;
    int s = row_ptr[i], e = row_ptr[i + 1];
    float a = 0.0f;
    for (int base = s; base < e; base += 64) {
        int idx = base + lane;
        int cl = 0; float vl = 0.0f;
        if (idx < e) { int2 p = ecv[idx]; cl = p.x; vl = __int_as_float(p.y); }
        int cnt = min(64, e - base);
        int cnt8 = (cnt + 7) & ~7;
        for (int k = 0; k < cnt8; k += 8) {
#pragma unroll
            for (int u = 0; u < 8; ++u) {
                int c = __shfl(cl, k + u);
                float v = __shfl(vl, k + u);
                a += v * x[(size_t)c * 64 + lane];
            }
        }
    }
    float sq = a * a;
#pragma unroll
    for (int off = 32; off; off >>= 1) sq += __shfl_xor(sq, off);
    float norm = sqrtf(sq);
    float a3 = acc3[(size_t)i * 64 + lane] + a / fmaxf(norm, 1e-12f);
    float a2 = mixed[(size_t)i * 64 + lane];
    float vv = vvec[lane];
    float w2 = a2 * vv, w3 = a3 * vv;
#pragma unroll
    for (int off = 32; off; off >>= 1) {
        w2 += __shfl_xor(w2, off);
        w3 += __shfl_xor(w3, off);
    }
    float m = fmaxf(w2, w3);
    float x2 = __expf(w2 - m), x3 = __expf(w3 - m);
    float inv = 1.0f / (x2 + x3);
    float s2 = x2 * inv, s3 = x3 * inv;
    mixed[(size_t)i * 64 + lane] = s2 * a2 + s3 * a3;
    if (lane == 0) { score[(size_t)i * 2] = s2; score[(size_t)i * 2 + 1] = s3; }
}

// v[k] = sum_j att_m[k][j] * att[j]
__global__ void vvec_kernel(const float* __restrict__ att_m, const float* __restrict__ att,
                            float* __restrict__ v) {
    int k = threadIdx.x;
    float s = 0.0f;
    for (int j = 0; j < 64; ++j) s += att_m[k * 64 + j] * att[j];
    v[k] = s;
}

extern "C" void kernel_launch(void* const* d_in, const int* in_sizes, int n_in,
                              void* d_out, int out_size, void* d_ws, size_t ws_size,
                              hipStream_t stream) {
    const float* user_emb = (const float*)d_in[0];
    const float* W0 = (const float*)d_in[1];
    const float* b0 = (const float*)d_in[2];
    const float* W1 = (const float*)d_in[3];
    const float* b1 = (const float*)d_in[4];
    const float* att = (const float*)d_in[5];
    const float* att_m = (const float*)d_in[6];
    const int* item_rows = (const int*)d_in[7];
    const int* item_cols = (const int*)d_in[8];
    const float* item_vals = (const float*)d_in[9];
    const int* user_rows = (const int*)d_in[10];
    const int* user_cols = (const int*)d_in[11];
    const float* user_vals = (const float*)d_in[12];

    float* out = (float*)d_out;
    float* mixed = out;                          // N*64, doubles as acc2
    float* score = out + (size_t)N_NODE * 64;

    char* w = (char*)d_ws;
    float* acc3 = (float*)w;   w += (size_t)N_NODE * 64 * 4;
    float* u_cur = (float*)w;  w += (size_t)N_NODE * 64 * 4;
    float* u_nxt = (float*)w;  w += (size_t)N_NODE * 64 * 4;
    int* row_ptr = (int*)w;    w += ((size_t)CSR_N + 2) * 4;
    int* fill = (int*)w;       w += (size_t)CSR_N * 4;
    int2* ecv = (int2*)w;      w += (size_t)TOT_E * 8;
    float* vvec = (float*)w;   w += 256;
    int* bsum = (int*)w;       w += ((SCAN_BLOCKS + 1) & ~1) * 4;
    int* boff = (int*)w;       w += ((SCAN_BLOCKS + 1) & ~1) * 4;

    const int NB4 = (N_NODE + 3) / 4;
    const int EB2 = (TOT_E + 255) / 256;
    const int* rp_item = row_ptr;
    const int* rp_user = row_ptr + N_NODE;

    // unified CSR build for both graphs
    hipMemsetAsync(fill, 0, (size_t)CSR_N * 4, stream);
    hist2_kernel<<<EB2, 256, 0, stream>>>(item_rows, user_rows, fill);
    scan1_kernel<<<SCAN_BLOCKS, 256, 0, stream>>>(fill, bsum, CSR_N);
    scan2_kernel<<<1, 512, 0, stream>>>(bsum, boff);
    scan3_kernel<<<SCAN_BLOCKS, 256, 0, stream>>>(fill, boff, row_ptr, fill, CSR_N);
    scatter2_kernel<<<EB2, 256, 0, stream>>>(item_rows, item_cols, item_vals,
                                             user_rows, user_cols, user_vals, fill, ecv);
    vvec_kernel<<<1, 64, 0, stream>>>(att_m, att, vvec);

    // channel 2: item graph, acc lives in d_out (mixed region)
    gate_kernel<<<NB4, 256, 0, stream>>>(user_emb, W0, b0, mixed, u_cur, N_NODE);
    spmm_norm_acc<true><<<NB4, 256, 0, stream>>>(rp_item, ecv, u_cur, u_nxt, mixed, N_NODE);
    spmm_norm_acc<true><<<NB4, 256, 0, stream>>>(rp_item, ecv, u_nxt, u_cur, mixed, N_NODE);
    spmm_norm_acc<false><<<NB4, 256, 0, stream>>>(rp_item, ecv, u_cur, nullptr, mixed, N_NODE);

    // channel 3: user graph
    gate_kernel<<<NB4, 256, 0, stream>>>(user_emb, W1, b1, acc3, u_cur, N_NODE);
    spmm_norm_acc<true><<<NB4, 256, 0, stream>>>(rp_user, ecv, u_cur, u_nxt, acc3, N_NODE);
    spmm_norm_acc<true><<<NB4, 256, 0, stream>>>(rp_user, ecv, u_nxt, u_cur, acc3, N_NODE);
    spmm_norm_mix<<<NB4, 256, 0, stream>>>(rp_user, ecv, u_cur, acc3, mixed, vvec, score, N_NODE);
}